// Round 3
// baseline (161.917 us; speedup 1.0000x reference)
//
#include <hip/hip_runtime.h>
#include <hip/hip_bf16.h>

#define BB 64
#define TT 512
#define HH 768
#define LL 9

// ---------------------------------------------------------------------------
// Kernel A: logits = relu(hidden @ W + b)   [32768 x 9]
// wave-per-4-rows, W^T staged in LDS, float4 loads of hidden.
// ---------------------------------------------------------------------------
__global__ __launch_bounds__(256) void logits_kernel(
    const float* __restrict__ hidden,   // [32768][768]
    const float* __restrict__ W,        // [768][9]
    const float* __restrict__ bias,     // [9]
    float* __restrict__ logits)         // [32768][9]
{
    __shared__ __align__(16) float WT[LL][HH];   // transposed W
    __shared__ float bsh[LL];

    const int tid = threadIdx.x;
    for (int idx = tid; idx < HH * LL; idx += 256) {
        int k = idx / LL, l = idx % LL;
        WT[l][k] = W[idx];
    }
    if (tid < LL) bsh[tid] = bias[tid];
    __syncthreads();

    const int wave = tid >> 6;
    const int lane = tid & 63;
    const long base_row = (long)blockIdx.x * 16 + wave * 4;
    const float* hrow = hidden + base_row * HH;

    float acc[4][LL];
#pragma unroll
    for (int r = 0; r < 4; ++r)
#pragma unroll
        for (int l = 0; l < LL; ++l) acc[r][l] = 0.f;

#pragma unroll
    for (int it = 0; it < 3; ++it) {
        const int k = it * 256 + lane * 4;
        float4 h[4];
#pragma unroll
        for (int r = 0; r < 4; ++r)
            h[r] = *(const float4*)(hrow + (long)r * HH + k);
#pragma unroll
        for (int l = 0; l < LL; ++l) {
            float4 w4 = *(const float4*)(&WT[l][k]);
#pragma unroll
            for (int r = 0; r < 4; ++r) {
                acc[r][l] += h[r].x * w4.x + h[r].y * w4.y
                           + h[r].z * w4.z + h[r].w * w4.w;
            }
        }
    }

    // butterfly reduce each of the 36 sums across the 64 lanes
#pragma unroll
    for (int r = 0; r < 4; ++r)
#pragma unroll
        for (int l = 0; l < LL; ++l) {
            float v = acc[r][l];
#pragma unroll
            for (int off = 32; off; off >>= 1) v += __shfl_xor(v, off, 64);
            acc[r][l] = v;
        }

    if (lane < LL) {
#pragma unroll
        for (int r = 0; r < 4; ++r) {
            float v = acc[r][0];
#pragma unroll
            for (int l = 1; l < LL; ++l) v = (lane == l) ? acc[r][l] : v;
            v += bsh[lane];
            v = v > 0.f ? v : 0.f;
            logits[(base_row + r) * LL + lane] = v;
        }
    }
}

// ---------------------------------------------------------------------------
// Kernel B: per-batch CRF.  Block = 128 threads (2 waves).
//   wave 0: unary/binary partials + logsumexp forward scan -> ll[b]
//   wave 1: Viterbi forward (backpointers) + parallel compose backtrace
// Cross-lane state broadcast via one LDS write + 3 broadcast reads per step
// (same-wave DS ops are pipe-ordered; same-address reads are conflict-free).
// ---------------------------------------------------------------------------
__global__ __launch_bounds__(128) void crf_kernel(
    const float* __restrict__ logits,   // [64][512][9]
    const float* __restrict__ trans,    // [9][9]
    const int*  __restrict__ tags,      // [64][512]
    const int*  __restrict__ lengths,   // [64]
    float* __restrict__ ll,             // [64]
    float* __restrict__ out_decode)     // [64][512] (floats)
{
    const int b    = blockIdx.x;
    const int tid  = threadIdx.x;
    const int wave = tid >> 6;
    const int lane = tid & 63;

    __shared__ __align__(16) float lg[TT][LL];
    __shared__ __align__(16) int   tg[TT];
    __shared__ unsigned char bpB[TT][LL];
    __shared__ float trS[LL * LL];
    __shared__ float score_parts[4];
    __shared__ __align__(16) float bcastA[12];   // wave 0 state broadcast
    __shared__ __align__(16) float bcastV[12];   // wave 1 state broadcast

    const int len = lengths[b];
    const float* lgg = logits + (size_t)b * TT * LL;
    // vectorized staging: 4608 floats = 1152 float4
    {
        const float4* src = (const float4*)lgg;
        float4* dst = (float4*)&lg[0][0];
        for (int i = tid; i < (TT * LL) / 4; i += 128) dst[i] = src[i];
    }
    {
        const int4* src = (const int4*)(tags + (size_t)b * TT);
        int4* dst = (int4*)tg;
        for (int i = tid; i < TT / 4; i += 128) dst[i] = src[i];
    }
    for (int idx = tid; idx < LL * LL; idx += 128) trS[idx] = trans[idx];
    __syncthreads();

    // ---- unary + binary gold scores (parallel over t, both waves) ----
    float u = 0.f, bs = 0.f;
    for (int t = tid; t < len; t += 128) u += lg[t][tg[t]];
    for (int t = tid + 1; t < len; t += 128) bs += trS[tg[t - 1] * LL + tg[t]];
#pragma unroll
    for (int off = 32; off; off >>= 1) {
        u  += __shfl_xor(u, off, 64);
        bs += __shfl_xor(bs, off, 64);
    }
    if (lane == 0) { score_parts[wave * 2] = u; score_parts[wave * 2 + 1] = bs; }
    __syncthreads();

    const int j = (lane < LL) ? lane : (LL - 1);
    float trc[LL];                 // transitions column j
#pragma unroll
    for (int i = 0; i < LL; ++i) trc[i] = trS[i * LL + j];

    if (wave == 0) {
        // ---------------- logsumexp forward scan ----------------
        if (lane < LL) bcastA[lane] = lg[0][lane];

        for (int t = 1; t < len; ++t) {
            float4 a03 = *(const float4*)&bcastA[0];
            float4 a47 = *(const float4*)&bcastA[4];
            float  a8  = bcastA[8];
            float s0 = a03.x + trc[0], s1 = a03.y + trc[1];
            float s2 = a03.z + trc[2], s3 = a03.w + trc[3];
            float s4 = a47.x + trc[4], s5 = a47.y + trc[5];
            float s6 = a47.z + trc[6], s7 = a47.w + trc[7];
            float s8 = a8    + trc[8];
            float m = fmaxf(fmaxf(fmaxf(fmaxf(s0, s1), fmaxf(s2, s3)),
                                  fmaxf(fmaxf(s4, s5), fmaxf(s6, s7))),
                            s8);
            float sum = 0.f;
            sum += __expf(s0 - m); sum += __expf(s1 - m); sum += __expf(s2 - m);
            sum += __expf(s3 - m); sum += __expf(s4 - m); sum += __expf(s5 - m);
            sum += __expf(s6 - m); sum += __expf(s7 - m); sum += __expf(s8 - m);
            float na = m + __logf(sum) + lg[t][j];
            if (lane < LL) bcastA[j] = na;
        }
        {
            float4 a03 = *(const float4*)&bcastA[0];
            float4 a47 = *(const float4*)&bcastA[4];
            float  a8  = bcastA[8];
            float m = fmaxf(fmaxf(fmaxf(fmaxf(a03.x, a03.y), fmaxf(a03.z, a03.w)),
                                  fmaxf(fmaxf(a47.x, a47.y), fmaxf(a47.z, a47.w))),
                            a8);
            float sum = 0.f;
            sum += __expf(a03.x - m); sum += __expf(a03.y - m); sum += __expf(a03.z - m);
            sum += __expf(a03.w - m); sum += __expf(a47.x - m); sum += __expf(a47.y - m);
            sum += __expf(a47.z - m); sum += __expf(a47.w - m); sum += __expf(a8 - m);
            float log_norm = m + __logf(sum);
            if (lane == 0) {
                float unary  = score_parts[0] + score_parts[2];
                float binary = score_parts[1] + score_parts[3];
                ll[b] = unary + binary - log_norm;
            }
        }
    } else {
        // ---------------- Viterbi forward ----------------
        if (lane < LL) bcastV[lane] = lg[0][lane];

        for (int t = 1; t < len; ++t) {
            float4 v03 = *(const float4*)&bcastV[0];
            float4 v47 = *(const float4*)&bcastV[4];
            float  v8  = bcastV[8];
            float s0 = v03.x + trc[0], s1 = v03.y + trc[1];
            float s2 = v03.z + trc[2], s3 = v03.w + trc[3];
            float s4 = v47.x + trc[4], s5 = v47.y + trc[5];
            float s6 = v47.z + trc[6], s7 = v47.w + trc[7];
            float s8 = v8    + trc[8];
            // first-max tree argmax (identical result to sequential v > best)
            float c1v = (s1 > s0) ? s1 : s0;  int c1i = (s1 > s0) ? 1 : 0;
            float c2v = (s3 > s2) ? s3 : s2;  int c2i = (s3 > s2) ? 3 : 2;
            float c3v = (s5 > s4) ? s5 : s4;  int c3i = (s5 > s4) ? 5 : 4;
            float c4v = (s7 > s6) ? s7 : s6;  int c4i = (s7 > s6) ? 7 : 6;
            float d1v = (c2v > c1v) ? c2v : c1v;  int d1i = (c2v > c1v) ? c2i : c1i;
            float d2v = (c4v > c3v) ? c4v : c3v;  int d2i = (c4v > c3v) ? c4i : c3i;
            float e1v = (d2v > d1v) ? d2v : d1v;  int e1i = (d2v > d1v) ? d2i : d1i;
            float bv  = (s8 > e1v) ? s8 : e1v;    int bi  = (s8 > e1v) ? 8 : e1i;
            if (lane < LL) bpB[t][lane] = (unsigned char)bi;
            float ns = bv + lg[t][j];
            if (lane < LL) bcastV[j] = ns;
        }

        // last_tag = first-max argmax of final state
        int last_tag;
        {
            float4 v03 = *(const float4*)&bcastV[0];
            float4 v47 = *(const float4*)&bcastV[4];
            float  v8  = bcastV[8];
            float s0 = v03.x, s1 = v03.y, s2 = v03.z, s3 = v03.w;
            float s4 = v47.x, s5 = v47.y, s6 = v47.z, s7 = v47.w;
            float s8 = v8;
            float c1v = (s1 > s0) ? s1 : s0;  int c1i = (s1 > s0) ? 1 : 0;
            float c2v = (s3 > s2) ? s3 : s2;  int c2i = (s3 > s2) ? 3 : 2;
            float c3v = (s5 > s4) ? s5 : s4;  int c3i = (s5 > s4) ? 5 : 4;
            float c4v = (s7 > s6) ? s7 : s6;  int c4i = (s7 > s6) ? 7 : 6;
            float d1v = (c2v > c1v) ? c2v : c1v;  int d1i = (c2v > c1v) ? c2i : c1i;
            float d2v = (c4v > c3v) ? c4v : c3v;  int d2i = (c4v > c3v) ? c4i : c3i;
            float e1v = (d2v > d1v) ? d2v : d1v;  int e1i = (d2v > d1v) ? d2i : d1i;
            last_tag = (s8 > e1v) ? 8 : e1i;
        }

        // ---------------- compose-based parallel backtrace ----------------
        const unsigned long long IDENT = 0x876543210ULL;
        unsigned long long f[8];
        const int t0 = lane * 8;
#pragma unroll
        for (int m2 = 0; m2 < 8; ++m2) {
            int t = t0 + m2;
            unsigned long long F = IDENT;
            if (t >= 1 && t < len) {
                F = 0ULL;
#pragma unroll
                for (int jj = 0; jj < LL; ++jj)
                    F |= ((unsigned long long)bpB[t][jj]) << (4 * jj);
            }
            f[m2] = F;
        }
        // chunk composition h = f[0] o f[1] o ... o f[7]
        unsigned long long h = f[7];
#pragma unroll
        for (int m2 = 6; m2 >= 0; --m2) {
            unsigned long long hn = 0ULL;
#pragma unroll
            for (int jj = 0; jj < LL; ++jj) {
                int v = (int)((h >> (4 * jj)) & 15ULL);
                int w = (int)((f[m2] >> (4 * v)) & 15ULL);
                hn |= ((unsigned long long)w) << (4 * jj);
            }
            h = hn;
        }
        // serial chunk-boundary walk (all lanes redundantly)
        int tag = last_tag;
        int entry = last_tag;
        for (int l2 = 63; l2 >= 0; --l2) {
            unsigned long long g = __shfl(h, l2, 64);
            if (l2 == lane) entry = tag;
            tag = (int)((g >> (4 * tag)) & 15ULL);
        }
        // walk own 8-step chunk, emitting decode
        float* dec = out_decode + (size_t)b * TT;
        int e = entry;
        {
            int t = t0 + 7;
            dec[t] = (t < len) ? (float)e : 0.f;
        }
#pragma unroll
        for (int m2 = 7; m2 >= 1; --m2) {
            e = (int)((f[m2] >> (4 * e)) & 15ULL);
            int t = t0 + m2 - 1;
            dec[t] = (t < len) ? (float)e : 0.f;
        }
    }
}

// ---------------------------------------------------------------------------
// Kernel C: loss = -mean(ll)
// ---------------------------------------------------------------------------
__global__ __launch_bounds__(64) void loss_kernel(const float* __restrict__ ll,
                                                  float* __restrict__ out)
{
    const int lane = threadIdx.x;
    float v = ll[lane];
#pragma unroll
    for (int off = 32; off; off >>= 1) v += __shfl_xor(v, off, 64);
    if (lane == 0) out[0] = -v * (1.0f / 64.0f);
}

extern "C" void kernel_launch(void* const* d_in, const int* in_sizes, int n_in,
                              void* d_out, int out_size, void* d_ws, size_t ws_size,
                              hipStream_t stream)
{
    const float* hidden  = (const float*)d_in[0];
    const float* W       = (const float*)d_in[1];
    const float* bias    = (const float*)d_in[2];
    const float* trans   = (const float*)d_in[3];
    const int*   tags    = (const int*)d_in[4];
    const int*   lengths = (const int*)d_in[5];

    float* out = (float*)d_out;
    float* logits = (float*)d_ws;                       // 32768*9 floats
    float* ll     = logits + (size_t)BB * TT * LL;      // 64 floats

    logits_kernel<<<2048, 256, 0, stream>>>(hidden, W, bias, logits);
    crf_kernel<<<BB, 128, 0, stream>>>(logits, trans, tags, lengths, ll, out + 1);
    loss_kernel<<<1, 64, 0, stream>>>(ll, out);
}

// Round 8
// 142.518 us; speedup vs baseline: 1.1361x; 1.1361x over previous
//
#include <hip/hip_runtime.h>
#include <hip/hip_bf16.h>

#define BB 64
#define TT 512
#define HH 768
#define LL 9

__device__ __forceinline__ float rlane(float v, int i) {
    return __uint_as_float((unsigned)__builtin_amdgcn_readlane((int)__float_as_uint(v), i));
}

// ---------------------------------------------------------------------------
// Kernel A: logits = relu(hidden @ W + b)   [32768 x 9]
// wave-per-4-rows, W^T staged in LDS, float4 loads of hidden.
// ---------------------------------------------------------------------------
__global__ __launch_bounds__(256) void logits_kernel(
    const float* __restrict__ hidden,   // [32768][768]
    const float* __restrict__ W,        // [768][9]
    const float* __restrict__ bias,     // [9]
    float* __restrict__ logits)         // [32768][9]
{
    __shared__ __align__(16) float WT[LL][HH];   // transposed W
    __shared__ float bsh[LL];

    const int tid = threadIdx.x;
    for (int idx = tid; idx < HH * LL; idx += 256) {
        int k = idx / LL, l = idx % LL;
        WT[l][k] = W[idx];
    }
    if (tid < LL) bsh[tid] = bias[tid];
    __syncthreads();

    const int wave = tid >> 6;
    const int lane = tid & 63;
    const long base_row = (long)blockIdx.x * 16 + wave * 4;
    const float* hrow = hidden + base_row * HH;

    float acc[4][LL];
#pragma unroll
    for (int r = 0; r < 4; ++r)
#pragma unroll
        for (int l = 0; l < LL; ++l) acc[r][l] = 0.f;

#pragma unroll
    for (int it = 0; it < 3; ++it) {
        const int k = it * 256 + lane * 4;
        float4 h[4];
#pragma unroll
        for (int r = 0; r < 4; ++r)
            h[r] = *(const float4*)(hrow + (long)r * HH + k);
#pragma unroll
        for (int l = 0; l < LL; ++l) {
            float4 w4 = *(const float4*)(&WT[l][k]);
#pragma unroll
            for (int r = 0; r < 4; ++r) {
                acc[r][l] += h[r].x * w4.x + h[r].y * w4.y
                           + h[r].z * w4.z + h[r].w * w4.w;
            }
        }
    }

    // butterfly reduce each of the 36 sums across the 64 lanes
#pragma unroll
    for (int r = 0; r < 4; ++r)
#pragma unroll
        for (int l = 0; l < LL; ++l) {
            float v = acc[r][l];
#pragma unroll
            for (int off = 32; off; off >>= 1) v += __shfl_xor(v, off, 64);
            acc[r][l] = v;
        }

    if (lane < LL) {
#pragma unroll
        for (int r = 0; r < 4; ++r) {
            float v = acc[r][0];
#pragma unroll
            for (int l = 1; l < LL; ++l) v = (lane == l) ? acc[r][l] : v;
            v += bsh[lane];
            v = v > 0.f ? v : 0.f;
            logits[(base_row + r) * LL + lane] = v;
        }
    }
}

// ---------------------------------------------------------------------------
// Kernel B: per-batch CRF.  Block = 128 threads (2 waves).
//   wave 0: unary/binary partials + logsumexp forward scan -> ll[b]
//   wave 1: Viterbi forward (backpointers) + parallel compose backtrace
// Cross-lane state broadcast via v_readlane into SGPRs (VALU-only chain —
// no DS-pipe op on the critical path; lg[t][j] prefetched 1 iter ahead).
// ---------------------------------------------------------------------------
__global__ __launch_bounds__(128) void crf_kernel(
    const float* __restrict__ logits,   // [64][512][9]
    const float* __restrict__ trans,    // [9][9]
    const int*  __restrict__ tags,      // [64][512]
    const int*  __restrict__ lengths,   // [64]
    float* __restrict__ ll,             // [64]
    float* __restrict__ out_decode)     // [64][512] (floats)
{
    const int b    = blockIdx.x;
    const int tid  = threadIdx.x;
    const int wave = tid >> 6;
    const int lane = tid & 63;

    __shared__ __align__(16) float lg[TT][LL];
    __shared__ __align__(16) int   tg[TT];
    __shared__ unsigned char bpB[TT][LL];
    __shared__ float trS[LL * LL];
    __shared__ float score_parts[4];

    const int len = lengths[b];
    const float* lgg = logits + (size_t)b * TT * LL;
    {
        const float4* src = (const float4*)lgg;
        float4* dst = (float4*)&lg[0][0];
        for (int i = tid; i < (TT * LL) / 4; i += 128) dst[i] = src[i];
    }
    {
        const int4* src = (const int4*)(tags + (size_t)b * TT);
        int4* dst = (int4*)tg;
        for (int i = tid; i < TT / 4; i += 128) dst[i] = src[i];
    }
    for (int idx = tid; idx < LL * LL; idx += 128) trS[idx] = trans[idx];
    __syncthreads();

    // ---- unary + binary gold scores (parallel over t, both waves) ----
    float u = 0.f, bs = 0.f;
    for (int t = tid; t < len; t += 128) u += lg[t][tg[t]];
    for (int t = tid + 1; t < len; t += 128) bs += trS[tg[t - 1] * LL + tg[t]];
#pragma unroll
    for (int off = 32; off; off >>= 1) {
        u  += __shfl_xor(u, off, 64);
        bs += __shfl_xor(bs, off, 64);
    }
    if (lane == 0) { score_parts[wave * 2] = u; score_parts[wave * 2 + 1] = bs; }
    __syncthreads();

    const int j = (lane < LL) ? lane : (LL - 1);
    float trc[LL];                 // transitions column j
#pragma unroll
    for (int i = 0; i < LL; ++i) trc[i] = trS[i * LL + j];

    if (wave == 0) {
        // ---------------- logsumexp forward scan ----------------
        float a0, a1, a2, a3, a4, a5, a6, a7, a8;
        {
            float lg0 = lg[0][j];
            a0 = rlane(lg0, 0); a1 = rlane(lg0, 1); a2 = rlane(lg0, 2);
            a3 = rlane(lg0, 3); a4 = rlane(lg0, 4); a5 = rlane(lg0, 5);
            a6 = rlane(lg0, 6); a7 = rlane(lg0, 7); a8 = rlane(lg0, 8);
        }
        float lg_cur = lg[1][j];
        for (int t = 1; t < len; ++t) {
            int tn = (t + 1 < TT) ? t + 1 : TT - 1;     // uniform
            float lg_next = lg[tn][j];                   // off-chain prefetch
            float s0 = a0 + trc[0], s1 = a1 + trc[1];
            float s2 = a2 + trc[2], s3 = a3 + trc[3];
            float s4 = a4 + trc[4], s5 = a5 + trc[5];
            float s6 = a6 + trc[6], s7 = a7 + trc[7];
            float s8 = a8 + trc[8];
            float m = fmaxf(fmaxf(fmaxf(fmaxf(s0, s1), fmaxf(s2, s3)),
                                  fmaxf(fmaxf(s4, s5), fmaxf(s6, s7))),
                            s8);
            float sum = 0.f;
            sum += __expf(s0 - m); sum += __expf(s1 - m); sum += __expf(s2 - m);
            sum += __expf(s3 - m); sum += __expf(s4 - m); sum += __expf(s5 - m);
            sum += __expf(s6 - m); sum += __expf(s7 - m); sum += __expf(s8 - m);
            float na = m + __logf(sum) + lg_cur;
            a0 = rlane(na, 0); a1 = rlane(na, 1); a2 = rlane(na, 2);
            a3 = rlane(na, 3); a4 = rlane(na, 4); a5 = rlane(na, 5);
            a6 = rlane(na, 6); a7 = rlane(na, 7); a8 = rlane(na, 8);
            lg_cur = lg_next;
        }
        {
            float m = fmaxf(fmaxf(fmaxf(fmaxf(a0, a1), fmaxf(a2, a3)),
                                  fmaxf(fmaxf(a4, a5), fmaxf(a6, a7))),
                            a8);
            float sum = 0.f;
            sum += __expf(a0 - m); sum += __expf(a1 - m); sum += __expf(a2 - m);
            sum += __expf(a3 - m); sum += __expf(a4 - m); sum += __expf(a5 - m);
            sum += __expf(a6 - m); sum += __expf(a7 - m); sum += __expf(a8 - m);
            float log_norm = m + __logf(sum);
            if (lane == 0) {
                float unary  = score_parts[0] + score_parts[2];
                float binary = score_parts[1] + score_parts[3];
                ll[b] = unary + binary - log_norm;
            }
        }
    } else {
        // ---------------- Viterbi forward ----------------
        float a0, a1, a2, a3, a4, a5, a6, a7, a8;
        {
            float lg0 = lg[0][j];
            a0 = rlane(lg0, 0); a1 = rlane(lg0, 1); a2 = rlane(lg0, 2);
            a3 = rlane(lg0, 3); a4 = rlane(lg0, 4); a5 = rlane(lg0, 5);
            a6 = rlane(lg0, 6); a7 = rlane(lg0, 7); a8 = rlane(lg0, 8);
        }
        float lg_cur = lg[1][j];
        for (int t = 1; t < len; ++t) {
            int tn = (t + 1 < TT) ? t + 1 : TT - 1;
            float lg_next = lg[tn][j];
            float s0 = a0 + trc[0], s1 = a1 + trc[1];
            float s2 = a2 + trc[2], s3 = a3 + trc[3];
            float s4 = a4 + trc[4], s5 = a5 + trc[5];
            float s6 = a6 + trc[6], s7 = a7 + trc[7];
            float s8 = a8 + trc[8];
            // first-max tree argmax (identical result to sequential v > best)
            float c1v = (s1 > s0) ? s1 : s0;  int c1i = (s1 > s0) ? 1 : 0;
            float c2v = (s3 > s2) ? s3 : s2;  int c2i = (s3 > s2) ? 3 : 2;
            float c3v = (s5 > s4) ? s5 : s4;  int c3i = (s5 > s4) ? 5 : 4;
            float c4v = (s7 > s6) ? s7 : s6;  int c4i = (s7 > s6) ? 7 : 6;
            float d1v = (c2v > c1v) ? c2v : c1v;  int d1i = (c2v > c1v) ? c2i : c1i;
            float d2v = (c4v > c3v) ? c4v : c3v;  int d2i = (c4v > c3v) ? c4i : c3i;
            float e1v = (d2v > d1v) ? d2v : d1v;  int e1i = (d2v > d1v) ? d2i : d1i;
            float bv  = (s8 > e1v) ? s8 : e1v;    int bi  = (s8 > e1v) ? 8 : e1i;
            if (lane < LL) bpB[t][lane] = (unsigned char)bi;   // off-chain
            float ns = bv + lg_cur;
            a0 = rlane(ns, 0); a1 = rlane(ns, 1); a2 = rlane(ns, 2);
            a3 = rlane(ns, 3); a4 = rlane(ns, 4); a5 = rlane(ns, 5);
            a6 = rlane(ns, 6); a7 = rlane(ns, 7); a8 = rlane(ns, 8);
            lg_cur = lg_next;
        }

        // last_tag = first-max argmax of final state
        int last_tag;
        {
            float s0 = a0, s1 = a1, s2 = a2, s3 = a3;
            float s4 = a4, s5 = a5, s6 = a6, s7 = a7, s8 = a8;
            float c1v = (s1 > s0) ? s1 : s0;  int c1i = (s1 > s0) ? 1 : 0;
            float c2v = (s3 > s2) ? s3 : s2;  int c2i = (s3 > s2) ? 3 : 2;
            float c3v = (s5 > s4) ? s5 : s4;  int c3i = (s5 > s4) ? 5 : 4;
            float c4v = (s7 > s6) ? s7 : s6;  int c4i = (s7 > s6) ? 7 : 6;
            float d1v = (c2v > c1v) ? c2v : c1v;  int d1i = (c2v > c1v) ? c2i : c1i;
            float d2v = (c4v > c3v) ? c4v : c3v;  int d2i = (c4v > c3v) ? c4i : c3i;
            float e1v = (d2v > d1v) ? d2v : d1v;  int e1i = (d2v > d1v) ? d2i : d1i;
            last_tag = (s8 > e1v) ? 8 : e1i;
        }

        // ---------------- compose-based parallel backtrace ----------------
        const unsigned long long IDENT = 0x876543210ULL;
        unsigned long long f[8];
        const int t0 = lane * 8;
#pragma unroll
        for (int m2 = 0; m2 < 8; ++m2) {
            int t = t0 + m2;
            unsigned long long F = IDENT;
            if (t >= 1 && t < len) {
                F = 0ULL;
#pragma unroll
                for (int jj = 0; jj < LL; ++jj)
                    F |= ((unsigned long long)bpB[t][jj]) << (4 * jj);
            }
            f[m2] = F;
        }
        // chunk composition h = f[0] o f[1] o ... o f[7]
        unsigned long long h = f[7];
#pragma unroll
        for (int m2 = 6; m2 >= 0; --m2) {
            unsigned long long hn = 0ULL;
#pragma unroll
            for (int jj = 0; jj < LL; ++jj) {
                int v = (int)((h >> (4 * jj)) & 15ULL);
                int w = (int)((f[m2] >> (4 * v)) & 15ULL);
                hn |= ((unsigned long long)w) << (4 * jj);
            }
            h = hn;
        }
        // serial chunk-boundary walk via readlane (VALU, no DS pipe)
        const unsigned hlo = (unsigned)h, hhi = (unsigned)(h >> 32);
        int tag = last_tag;
        int entry = last_tag;
        for (int l2 = 63; l2 >= 0; --l2) {
            unsigned glo = (unsigned)__builtin_amdgcn_readlane((int)hlo, l2);
            unsigned ghi = (unsigned)__builtin_amdgcn_readlane((int)hhi, l2);
            unsigned long long g = ((unsigned long long)ghi << 32) | glo;
            if (l2 == lane) entry = tag;
            tag = (int)((g >> (4 * tag)) & 15ULL);
        }
        // walk own 8-step chunk, emitting decode
        float* dec = out_decode + (size_t)b * TT;
        int e = entry;
        {
            int t = t0 + 7;
            dec[t] = (t < len) ? (float)e : 0.f;
        }
#pragma unroll
        for (int m2 = 7; m2 >= 1; --m2) {
            e = (int)((f[m2] >> (4 * e)) & 15ULL);
            int t = t0 + m2 - 1;
            dec[t] = (t < len) ? (float)e : 0.f;
        }
    }
}

// ---------------------------------------------------------------------------
// Kernel C: loss = -mean(ll)
// ---------------------------------------------------------------------------
__global__ __launch_bounds__(64) void loss_kernel(const float* __restrict__ ll,
                                                  float* __restrict__ out)
{
    const int lane = threadIdx.x;
    float v = ll[lane];
#pragma unroll
    for (int off = 32; off; off >>= 1) v += __shfl_xor(v, off, 64);
    if (lane == 0) out[0] = -v * (1.0f / 64.0f);
}

extern "C" void kernel_launch(void* const* d_in, const int* in_sizes, int n_in,
                              void* d_out, int out_size, void* d_ws, size_t ws_size,
                              hipStream_t stream)
{
    const float* hidden  = (const float*)d_in[0];
    const float* W       = (const float*)d_in[1];
    const float* bias    = (const float*)d_in[2];
    const float* trans   = (const float*)d_in[3];
    const int*   tags    = (const int*)d_in[4];
    const int*   lengths = (const int*)d_in[5];

    float* out = (float*)d_out;
    float* logits = (float*)d_ws;                       // 32768*9 floats
    float* ll     = logits + (size_t)BB * TT * LL;      // 64 floats

    logits_kernel<<<2048, 256, 0, stream>>>(hidden, W, bias, logits);
    crf_kernel<<<BB, 128, 0, stream>>>(logits, trans, tags, lengths, ll, out + 1);
    loss_kernel<<<1, 64, 0, stream>>>(ll, out);
}

// Round 11
// 128.431 us; speedup vs baseline: 1.2607x; 1.1097x over previous
//
#include <hip/hip_runtime.h>
#include <hip/hip_bf16.h>

#define BB 64
#define TT 512
#define HH 768
#define LL 9
#define TS 516   // padded lgT row stride (bank-spreads lanes: (j*516+t)%32 = (4j+t)%32)

__device__ __forceinline__ float rlane(float v, int i) {
    return __uint_as_float((unsigned)__builtin_amdgcn_readlane((int)__float_as_uint(v), i));
}

// ---------------------------------------------------------------------------
// Kernel A: logits = relu(hidden @ W + b)   [32768 x 9]
// ---------------------------------------------------------------------------
__global__ __launch_bounds__(256) void logits_kernel(
    const float* __restrict__ hidden,   // [32768][768]
    const float* __restrict__ W,        // [768][9]
    const float* __restrict__ bias,     // [9]
    float* __restrict__ logits)         // [32768][9]
{
    __shared__ __align__(16) float WT[LL][HH];
    __shared__ float bsh[LL];

    const int tid = threadIdx.x;
    for (int idx = tid; idx < HH * LL; idx += 256) {
        int k = idx / LL, l = idx % LL;
        WT[l][k] = W[idx];
    }
    if (tid < LL) bsh[tid] = bias[tid];
    __syncthreads();

    const int wave = tid >> 6;
    const int lane = tid & 63;
    const long base_row = (long)blockIdx.x * 16 + wave * 4;
    const float* hrow = hidden + base_row * HH;

    float acc[4][LL];
#pragma unroll
    for (int r = 0; r < 4; ++r)
#pragma unroll
        for (int l = 0; l < LL; ++l) acc[r][l] = 0.f;

#pragma unroll
    for (int it = 0; it < 3; ++it) {
        const int k = it * 256 + lane * 4;
        float4 h[4];
#pragma unroll
        for (int r = 0; r < 4; ++r)
            h[r] = *(const float4*)(hrow + (long)r * HH + k);
#pragma unroll
        for (int l = 0; l < LL; ++l) {
            float4 w4 = *(const float4*)(&WT[l][k]);
#pragma unroll
            for (int r = 0; r < 4; ++r) {
                acc[r][l] += h[r].x * w4.x + h[r].y * w4.y
                           + h[r].z * w4.z + h[r].w * w4.w;
            }
        }
    }

#pragma unroll
    for (int r = 0; r < 4; ++r)
#pragma unroll
        for (int l = 0; l < LL; ++l) {
            float v = acc[r][l];
#pragma unroll
            for (int off = 32; off; off >>= 1) v += __shfl_xor(v, off, 64);
            acc[r][l] = v;
        }

    if (lane < LL) {
#pragma unroll
        for (int r = 0; r < 4; ++r) {
            float v = acc[r][0];
#pragma unroll
            for (int l = 1; l < LL; ++l) v = (lane == l) ? acc[r][l] : v;
            v += bsh[lane];
            v = v > 0.f ? v : 0.f;
            logits[(base_row + r) * LL + lane] = v;
        }
    }
}

// ---------------------------------------------------------------------------
// Kernel B: per-batch CRF.  Block = 128 threads (2 waves).
//   wave 0: logsumexp forward scan -> ll[b]
//   wave 1: Viterbi forward + compose backtrace -> decode
// Logits transposed in LDS (lgT[9][516]); per-lane row contiguous in t.
// Chunked 8-step bodies with double-buffered float4 loads issued one chunk
// ahead -> no per-step LDS round-trip on the dependent chain.
// State broadcast via v_readlane (VALU). Arithmetic identical to R8 kernel.
// ---------------------------------------------------------------------------
__global__ __launch_bounds__(128) void crf_kernel(
    const float* __restrict__ logits,   // [64][512][9]
    const float* __restrict__ trans,    // [9][9]
    const int*  __restrict__ tags,      // [64][512]
    const int*  __restrict__ lengths,   // [64]
    float* __restrict__ ll,             // [64]
    float* __restrict__ out_decode)     // [64][512] (floats)
{
    const int b    = blockIdx.x;
    const int tid  = threadIdx.x;
    const int wave = tid >> 6;
    const int lane = tid & 63;

    __shared__ __align__(16) float lgT[LL][TS];
    __shared__ __align__(16) int   tg[TT];
    __shared__ unsigned char bpB[TT][LL];
    __shared__ float trS[LL * LL];
    __shared__ float score_parts[4];

    const int len = lengths[b];
    const float* lgg = logits + (size_t)b * TT * LL;
    // staging: transpose [t][l] -> lgT[l][t]
    for (int i = tid; i < (TT * LL) / 4; i += 128) {
        float4 v = ((const float4*)lgg)[i];
        int base = 4 * i;
        lgT[(base    ) % LL][(base    ) / LL] = v.x;
        lgT[(base + 1) % LL][(base + 1) / LL] = v.y;
        lgT[(base + 2) % LL][(base + 2) / LL] = v.z;
        lgT[(base + 3) % LL][(base + 3) / LL] = v.w;
    }
    {
        const int4* src = (const int4*)(tags + (size_t)b * TT);
        int4* dst = (int4*)tg;
        for (int i = tid; i < TT / 4; i += 128) dst[i] = src[i];
    }
    for (int idx = tid; idx < LL * LL; idx += 128) trS[idx] = trans[idx];
    __syncthreads();

    // ---- unary + binary gold scores (parallel over t, both waves) ----
    float u = 0.f, bs = 0.f;
    for (int t = tid; t < len; t += 128) u += lgT[tg[t]][t];
    for (int t = tid + 1; t < len; t += 128) bs += trS[tg[t - 1] * LL + tg[t]];
#pragma unroll
    for (int off = 32; off; off >>= 1) {
        u  += __shfl_xor(u, off, 64);
        bs += __shfl_xor(bs, off, 64);
    }
    if (lane == 0) { score_parts[wave * 2] = u; score_parts[wave * 2 + 1] = bs; }
    __syncthreads();

    const int j = (lane < LL) ? lane : (LL - 1);
    float trc[LL];                 // transitions column j
#pragma unroll
    for (int i = 0; i < LL; ++i) trc[i] = trS[i * LL + j];

    const float* rowj = &lgT[j][0];

    if (wave == 0) {
        // ---------------- logsumexp forward scan ----------------
        float4 c0 = *(const float4*)(rowj);         // t 0..3
        float4 c1 = *(const float4*)(rowj + 4);     // t 4..7
        float4 n0 = *(const float4*)(rowj + 8);     // next chunk
        float4 n1 = *(const float4*)(rowj + 12);

        float a0, a1, a2, a3, a4, a5, a6, a7, a8;
        a0 = rlane(c0.x, 0); a1 = rlane(c0.x, 1); a2 = rlane(c0.x, 2);
        a3 = rlane(c0.x, 3); a4 = rlane(c0.x, 4); a5 = rlane(c0.x, 5);
        a6 = rlane(c0.x, 6); a7 = rlane(c0.x, 7); a8 = rlane(c0.x, 8);

#define LSTEP(LGV, TVAL)                                                     \
        { if ((TVAL) >= len) goto lse_done;                                  \
          float s0 = a0 + trc[0], s1 = a1 + trc[1];                          \
          float s2 = a2 + trc[2], s3 = a3 + trc[3];                          \
          float s4 = a4 + trc[4], s5 = a5 + trc[5];                          \
          float s6 = a6 + trc[6], s7 = a7 + trc[7];                          \
          float s8 = a8 + trc[8];                                            \
          float m = fmaxf(fmaxf(fmaxf(fmaxf(s0, s1), fmaxf(s2, s3)),        \
                                fmaxf(fmaxf(s4, s5), fmaxf(s6, s7))), s8);  \
          float sum = 0.f;                                                   \
          sum += __expf(s0 - m); sum += __expf(s1 - m); sum += __expf(s2 - m);\
          sum += __expf(s3 - m); sum += __expf(s4 - m); sum += __expf(s5 - m);\
          sum += __expf(s6 - m); sum += __expf(s7 - m); sum += __expf(s8 - m);\
          float na = m + __logf(sum) + (LGV);                                \
          a0 = rlane(na, 0); a1 = rlane(na, 1); a2 = rlane(na, 2);           \
          a3 = rlane(na, 3); a4 = rlane(na, 4); a5 = rlane(na, 5);           \
          a6 = rlane(na, 6); a7 = rlane(na, 7); a8 = rlane(na, 8); }

        // peeled chunk 0: t = 1..7
        LSTEP(c0.y, 1) LSTEP(c0.z, 2) LSTEP(c0.w, 3)
        LSTEP(c1.x, 4) LSTEP(c1.y, 5) LSTEP(c1.z, 6) LSTEP(c1.w, 7)

        for (int cb = 8; cb < TT; cb += 8) {
            c0 = n0; c1 = n1;
            if (cb + 8 < TT) {
                n0 = *(const float4*)(rowj + cb + 8);
                n1 = *(const float4*)(rowj + cb + 12);
            }
            LSTEP(c0.x, cb + 0) LSTEP(c0.y, cb + 1)
            LSTEP(c0.z, cb + 2) LSTEP(c0.w, cb + 3)
            LSTEP(c1.x, cb + 4) LSTEP(c1.y, cb + 5)
            LSTEP(c1.z, cb + 6) LSTEP(c1.w, cb + 7)
        }
lse_done: ;
        {
            float m = fmaxf(fmaxf(fmaxf(fmaxf(a0, a1), fmaxf(a2, a3)),
                                  fmaxf(fmaxf(a4, a5), fmaxf(a6, a7))),
                            a8);
            float sum = 0.f;
            sum += __expf(a0 - m); sum += __expf(a1 - m); sum += __expf(a2 - m);
            sum += __expf(a3 - m); sum += __expf(a4 - m); sum += __expf(a5 - m);
            sum += __expf(a6 - m); sum += __expf(a7 - m); sum += __expf(a8 - m);
            float log_norm = m + __logf(sum);
            if (lane == 0) {
                float unary  = score_parts[0] + score_parts[2];
                float binary = score_parts[1] + score_parts[3];
                ll[b] = unary + binary - log_norm;
            }
        }
    } else {
        // ---------------- Viterbi forward ----------------
        float4 c0 = *(const float4*)(rowj);
        float4 c1 = *(const float4*)(rowj + 4);
        float4 n0 = *(const float4*)(rowj + 8);
        float4 n1 = *(const float4*)(rowj + 12);

        float a0, a1, a2, a3, a4, a5, a6, a7, a8;
        a0 = rlane(c0.x, 0); a1 = rlane(c0.x, 1); a2 = rlane(c0.x, 2);
        a3 = rlane(c0.x, 3); a4 = rlane(c0.x, 4); a5 = rlane(c0.x, 5);
        a6 = rlane(c0.x, 6); a7 = rlane(c0.x, 7); a8 = rlane(c0.x, 8);

#define VSTEP(LGV, TVAL)                                                     \
        { if ((TVAL) >= len) goto vit_done;                                  \
          float s0 = a0 + trc[0], s1 = a1 + trc[1];                          \
          float s2 = a2 + trc[2], s3 = a3 + trc[3];                          \
          float s4 = a4 + trc[4], s5 = a5 + trc[5];                          \
          float s6 = a6 + trc[6], s7 = a7 + trc[7];                          \
          float s8 = a8 + trc[8];                                            \
          float c1v = (s1 > s0) ? s1 : s0;  int c1i = (s1 > s0) ? 1 : 0;    \
          float c2v = (s3 > s2) ? s3 : s2;  int c2i = (s3 > s2) ? 3 : 2;    \
          float c3v = (s5 > s4) ? s5 : s4;  int c3i = (s5 > s4) ? 5 : 4;    \
          float c4v = (s7 > s6) ? s7 : s6;  int c4i = (s7 > s6) ? 7 : 6;    \
          float d1v = (c2v > c1v) ? c2v : c1v;  int d1i = (c2v > c1v) ? c2i : c1i; \
          float d2v = (c4v > c3v) ? c4v : c3v;  int d2i = (c4v > c3v) ? c4i : c3i; \
          float e1v = (d2v > d1v) ? d2v : d1v;  int e1i = (d2v > d1v) ? d2i : d1i; \
          float bv  = (s8 > e1v) ? s8 : e1v;    int bi  = (s8 > e1v) ? 8 : e1i;    \
          if (lane < LL) bpB[TVAL][lane] = (unsigned char)bi;                \
          float ns = bv + (LGV);                                             \
          a0 = rlane(ns, 0); a1 = rlane(ns, 1); a2 = rlane(ns, 2);           \
          a3 = rlane(ns, 3); a4 = rlane(ns, 4); a5 = rlane(ns, 5);           \
          a6 = rlane(ns, 6); a7 = rlane(ns, 7); a8 = rlane(ns, 8); }

        VSTEP(c0.y, 1) VSTEP(c0.z, 2) VSTEP(c0.w, 3)
        VSTEP(c1.x, 4) VSTEP(c1.y, 5) VSTEP(c1.z, 6) VSTEP(c1.w, 7)

        for (int cb = 8; cb < TT; cb += 8) {
            c0 = n0; c1 = n1;
            if (cb + 8 < TT) {
                n0 = *(const float4*)(rowj + cb + 8);
                n1 = *(const float4*)(rowj + cb + 12);
            }
            VSTEP(c0.x, cb + 0) VSTEP(c0.y, cb + 1)
            VSTEP(c0.z, cb + 2) VSTEP(c0.w, cb + 3)
            VSTEP(c1.x, cb + 4) VSTEP(c1.y, cb + 5)
            VSTEP(c1.z, cb + 6) VSTEP(c1.w, cb + 7)
        }
vit_done: ;
        // last_tag = first-max argmax of final state
        int last_tag;
        {
            float s0 = a0, s1 = a1, s2 = a2, s3 = a3;
            float s4 = a4, s5 = a5, s6 = a6, s7 = a7, s8 = a8;
            float c1v = (s1 > s0) ? s1 : s0;  int c1i = (s1 > s0) ? 1 : 0;
            float c2v = (s3 > s2) ? s3 : s2;  int c2i = (s3 > s2) ? 3 : 2;
            float c3v = (s5 > s4) ? s5 : s4;  int c3i = (s5 > s4) ? 5 : 4;
            float c4v = (s7 > s6) ? s7 : s6;  int c4i = (s7 > s6) ? 7 : 6;
            float d1v = (c2v > c1v) ? c2v : c1v;  int d1i = (c2v > c1v) ? c2i : c1i;
            float d2v = (c4v > c3v) ? c4v : c3v;  int d2i = (c4v > c3v) ? c4i : c3i;
            float e1v = (d2v > d1v) ? d2v : d1v;  int e1i = (d2v > d1v) ? d2i : d1i;
            last_tag = (s8 > e1v) ? 8 : e1i;
        }

        // ---------------- compose-based parallel backtrace ----------------
        const unsigned long long IDENT = 0x876543210ULL;
        unsigned long long f[8];
        const int t0 = lane * 8;
#pragma unroll
        for (int m2 = 0; m2 < 8; ++m2) {
            int t = t0 + m2;
            unsigned long long F = IDENT;
            if (t >= 1 && t < len) {
                F = 0ULL;
#pragma unroll
                for (int jj = 0; jj < LL; ++jj)
                    F |= ((unsigned long long)bpB[t][jj]) << (4 * jj);
            }
            f[m2] = F;
        }
        unsigned long long h = f[7];
#pragma unroll
        for (int m2 = 6; m2 >= 0; --m2) {
            unsigned long long hn = 0ULL;
#pragma unroll
            for (int jj = 0; jj < LL; ++jj) {
                int v = (int)((h >> (4 * jj)) & 15ULL);
                int w = (int)((f[m2] >> (4 * v)) & 15ULL);
                hn |= ((unsigned long long)w) << (4 * jj);
            }
            h = hn;
        }
        const unsigned hlo = (unsigned)h, hhi = (unsigned)(h >> 32);
        int tag = last_tag;
        int entry = last_tag;
        for (int l2 = 63; l2 >= 0; --l2) {
            unsigned glo = (unsigned)__builtin_amdgcn_readlane((int)hlo, l2);
            unsigned ghi = (unsigned)__builtin_amdgcn_readlane((int)hhi, l2);
            unsigned long long g = ((unsigned long long)ghi << 32) | glo;
            if (l2 == lane) entry = tag;
            tag = (int)((g >> (4 * tag)) & 15ULL);
        }
        float* dec = out_decode + (size_t)b * TT;
        int e = entry;
        {
            int t = t0 + 7;
            dec[t] = (t < len) ? (float)e : 0.f;
        }
#pragma unroll
        for (int m2 = 7; m2 >= 1; --m2) {
            e = (int)((f[m2] >> (4 * e)) & 15ULL);
            int t = t0 + m2 - 1;
            dec[t] = (t < len) ? (float)e : 0.f;
        }
    }
}

// ---------------------------------------------------------------------------
// Kernel C: loss = -mean(ll)
// ---------------------------------------------------------------------------
__global__ __launch_bounds__(64) void loss_kernel(const float* __restrict__ ll,
                                                  float* __restrict__ out)
{
    const int lane = threadIdx.x;
    float v = ll[lane];
#pragma unroll
    for (int off = 32; off; off >>= 1) v += __shfl_xor(v, off, 64);
    if (lane == 0) out[0] = -v * (1.0f / 64.0f);
}

extern "C" void kernel_launch(void* const* d_in, const int* in_sizes, int n_in,
                              void* d_out, int out_size, void* d_ws, size_t ws_size,
                              hipStream_t stream)
{
    const float* hidden  = (const float*)d_in[0];
    const float* W       = (const float*)d_in[1];
    const float* bias    = (const float*)d_in[2];
    const float* trans   = (const float*)d_in[3];
    const int*   tags    = (const int*)d_in[4];
    const int*   lengths = (const int*)d_in[5];

    float* out = (float*)d_out;
    float* logits = (float*)d_ws;                       // 32768*9 floats
    float* ll     = logits + (size_t)BB * TT * LL;      // 64 floats

    logits_kernel<<<2048, 256, 0, stream>>>(hidden, W, bias, logits);
    crf_kernel<<<BB, 128, 0, stream>>>(logits, trans, tags, lengths, ll, out + 1);
    loss_kernel<<<1, 64, 0, stream>>>(ll, out);
}

// Round 12
// 106.628 us; speedup vs baseline: 1.5185x; 1.2045x over previous
//
#include <hip/hip_runtime.h>
#include <hip/hip_bf16.h>

#define BB 64
#define TT 512
#define HH 768
#define LL 9
#define TS 516   // padded lgT row stride

#define LOG2E 1.44269504088896340736f
#define LN2   0.69314718055994530942f

#if __has_builtin(__builtin_amdgcn_exp2f)
#define EXP2F(x) __builtin_amdgcn_exp2f(x)
#else
#define EXP2F(x) exp2f(x)
#endif
#if __has_builtin(__builtin_amdgcn_logf)
#define LOG2F(x) __builtin_amdgcn_logf(x)
#else
#define LOG2F(x) __log2f(x)
#endif

__device__ __forceinline__ float rlane(float v, int i) {
    return __uint_as_float((unsigned)__builtin_amdgcn_readlane((int)__float_as_uint(v), i));
}

// ---------------------------------------------------------------------------
// Kernel A: logits = relu(hidden @ W + b)   [32768 x 9]
// ---------------------------------------------------------------------------
__global__ __launch_bounds__(256) void logits_kernel(
    const float* __restrict__ hidden,   // [32768][768]
    const float* __restrict__ W,        // [768][9]
    const float* __restrict__ bias,     // [9]
    float* __restrict__ logits)         // [32768][9]
{
    __shared__ __align__(16) float WT[LL][HH];
    __shared__ float bsh[LL];

    const int tid = threadIdx.x;
    for (int idx = tid; idx < HH * LL; idx += 256) {
        int k = idx / LL, l = idx % LL;
        WT[l][k] = W[idx];
    }
    if (tid < LL) bsh[tid] = bias[tid];
    __syncthreads();

    const int wave = tid >> 6;
    const int lane = tid & 63;
    const long base_row = (long)blockIdx.x * 16 + wave * 4;
    const float* hrow = hidden + base_row * HH;

    float acc[4][LL];
#pragma unroll
    for (int r = 0; r < 4; ++r)
#pragma unroll
        for (int l = 0; l < LL; ++l) acc[r][l] = 0.f;

#pragma unroll
    for (int it = 0; it < 3; ++it) {
        const int k = it * 256 + lane * 4;
        float4 h[4];
#pragma unroll
        for (int r = 0; r < 4; ++r)
            h[r] = *(const float4*)(hrow + (long)r * HH + k);
#pragma unroll
        for (int l = 0; l < LL; ++l) {
            float4 w4 = *(const float4*)(&WT[l][k]);
#pragma unroll
            for (int r = 0; r < 4; ++r) {
                acc[r][l] += h[r].x * w4.x + h[r].y * w4.y
                           + h[r].z * w4.z + h[r].w * w4.w;
            }
        }
    }

#pragma unroll
    for (int r = 0; r < 4; ++r)
#pragma unroll
        for (int l = 0; l < LL; ++l) {
            float v = acc[r][l];
#pragma unroll
            for (int off = 32; off; off >>= 1) v += __shfl_xor(v, off, 64);
            acc[r][l] = v;
        }

    if (lane < LL) {
#pragma unroll
        for (int r = 0; r < 4; ++r) {
            float v = acc[r][0];
#pragma unroll
            for (int l = 1; l < LL; ++l) v = (lane == l) ? acc[r][l] : v;
            v += bsh[lane];
            v = v > 0.f ? v : 0.f;
            logits[(base_row + r) * LL + lane] = v;
        }
    }
}

// ---------------------------------------------------------------------------
// Kernel B: per-batch CRF.  Block = 128 threads (2 waves).
//   wave 0: logsumexp forward scan (exp2-domain: pure v_exp/v_log on chain)
//   wave 1: Viterbi forward + compose backtrace (bit-exact, unchanged)
// ---------------------------------------------------------------------------
__global__ __launch_bounds__(128) void crf_kernel(
    const float* __restrict__ logits,   // [64][512][9]
    const float* __restrict__ trans,    // [9][9]
    const int*  __restrict__ tags,      // [64][512]
    const int*  __restrict__ lengths,   // [64]
    float* __restrict__ ll,             // [64]
    float* __restrict__ out_decode)     // [64][512] (floats)
{
    const int b    = blockIdx.x;
    const int tid  = threadIdx.x;
    const int wave = tid >> 6;
    const int lane = tid & 63;

    __shared__ __align__(16) float lgT[LL][TS];
    __shared__ __align__(16) int   tg[TT];
    __shared__ unsigned char bpB[TT][LL];
    __shared__ float trS[LL * LL];
    __shared__ float score_parts[4];

    const int len = lengths[b];
    const float* lgg = logits + (size_t)b * TT * LL;
    // staging: transpose [t][l] -> lgT[l][t]
    for (int i = tid; i < (TT * LL) / 4; i += 128) {
        float4 v = ((const float4*)lgg)[i];
        int base = 4 * i;
        lgT[(base    ) % LL][(base    ) / LL] = v.x;
        lgT[(base + 1) % LL][(base + 1) / LL] = v.y;
        lgT[(base + 2) % LL][(base + 2) / LL] = v.z;
        lgT[(base + 3) % LL][(base + 3) / LL] = v.w;
    }
    {
        const int4* src = (const int4*)(tags + (size_t)b * TT);
        int4* dst = (int4*)tg;
        for (int i = tid; i < TT / 4; i += 128) dst[i] = src[i];
    }
    for (int idx = tid; idx < LL * LL; idx += 128) trS[idx] = trans[idx];
    __syncthreads();

    // ---- unary + binary gold scores (parallel over t, both waves) ----
    float u = 0.f, bs = 0.f;
    for (int t = tid; t < len; t += 128) u += lgT[tg[t]][t];
    for (int t = tid + 1; t < len; t += 128) bs += trS[tg[t - 1] * LL + tg[t]];
#pragma unroll
    for (int off = 32; off; off >>= 1) {
        u  += __shfl_xor(u, off, 64);
        bs += __shfl_xor(bs, off, 64);
    }
    if (lane == 0) { score_parts[wave * 2] = u; score_parts[wave * 2 + 1] = bs; }
    __syncthreads();

    const int j = (lane < LL) ? lane : (LL - 1);
    float trc[LL];                 // transitions column j
#pragma unroll
    for (int i = 0; i < LL; ++i) trc[i] = trS[i * LL + j];

    const float* rowj = &lgT[j][0];

    if (wave == 0) {
        // ------- logsumexp forward scan, exp2-domain (state = alpha*log2e) -------
#pragma unroll
        for (int i = 0; i < LL; ++i) trc[i] *= LOG2E;

        float4 c0 = *(const float4*)(rowj);         // t 0..3
        float4 c1 = *(const float4*)(rowj + 4);     // t 4..7
        float4 n0 = *(const float4*)(rowj + 8);     // next chunk
        float4 n1 = *(const float4*)(rowj + 12);
        c0.x *= LOG2E; c0.y *= LOG2E; c0.z *= LOG2E; c0.w *= LOG2E;
        c1.x *= LOG2E; c1.y *= LOG2E; c1.z *= LOG2E; c1.w *= LOG2E;
        n0.x *= LOG2E; n0.y *= LOG2E; n0.z *= LOG2E; n0.w *= LOG2E;
        n1.x *= LOG2E; n1.y *= LOG2E; n1.z *= LOG2E; n1.w *= LOG2E;

        float a0, a1, a2, a3, a4, a5, a6, a7, a8;
        a0 = rlane(c0.x, 0); a1 = rlane(c0.x, 1); a2 = rlane(c0.x, 2);
        a3 = rlane(c0.x, 3); a4 = rlane(c0.x, 4); a5 = rlane(c0.x, 5);
        a6 = rlane(c0.x, 6); a7 = rlane(c0.x, 7); a8 = rlane(c0.x, 8);

#define LSTEP(LGV, TVAL)                                                     \
        { if ((TVAL) >= len) goto lse_done;                                  \
          float s0 = a0 + trc[0], s1 = a1 + trc[1];                          \
          float s2 = a2 + trc[2], s3 = a3 + trc[3];                          \
          float s4 = a4 + trc[4], s5 = a5 + trc[5];                          \
          float s6 = a6 + trc[6], s7 = a7 + trc[7];                          \
          float s8 = a8 + trc[8];                                            \
          float m = fmaxf(fmaxf(fmaxf(fmaxf(s0, s1), fmaxf(s2, s3)),        \
                                fmaxf(fmaxf(s4, s5), fmaxf(s6, s7))), s8);  \
          float e0 = EXP2F(s0 - m), e1 = EXP2F(s1 - m), e2 = EXP2F(s2 - m); \
          float e3 = EXP2F(s3 - m), e4 = EXP2F(s4 - m), e5 = EXP2F(s5 - m); \
          float e6 = EXP2F(s6 - m), e7 = EXP2F(s7 - m), e8 = EXP2F(s8 - m); \
          float sum = (((e0 + e1) + (e2 + e3)) + ((e4 + e5) + (e6 + e7)))    \
                      + e8;                                                  \
          float na = m + LOG2F(sum) + (LGV);                                 \
          a0 = rlane(na, 0); a1 = rlane(na, 1); a2 = rlane(na, 2);           \
          a3 = rlane(na, 3); a4 = rlane(na, 4); a5 = rlane(na, 5);           \
          a6 = rlane(na, 6); a7 = rlane(na, 7); a8 = rlane(na, 8); }

        // peeled chunk 0: t = 1..7
        LSTEP(c0.y, 1) LSTEP(c0.z, 2) LSTEP(c0.w, 3)
        LSTEP(c1.x, 4) LSTEP(c1.y, 5) LSTEP(c1.z, 6) LSTEP(c1.w, 7)

        for (int cb = 8; cb < TT; cb += 8) {
            c0 = n0; c1 = n1;
            if (cb + 8 < TT) {
                n0 = *(const float4*)(rowj + cb + 8);
                n1 = *(const float4*)(rowj + cb + 12);
                n0.x *= LOG2E; n0.y *= LOG2E; n0.z *= LOG2E; n0.w *= LOG2E;
                n1.x *= LOG2E; n1.y *= LOG2E; n1.z *= LOG2E; n1.w *= LOG2E;
            }
            LSTEP(c0.x, cb + 0) LSTEP(c0.y, cb + 1)
            LSTEP(c0.z, cb + 2) LSTEP(c0.w, cb + 3)
            LSTEP(c1.x, cb + 4) LSTEP(c1.y, cb + 5)
            LSTEP(c1.z, cb + 6) LSTEP(c1.w, cb + 7)
        }
lse_done: ;
        {
            float m = fmaxf(fmaxf(fmaxf(fmaxf(a0, a1), fmaxf(a2, a3)),
                                  fmaxf(fmaxf(a4, a5), fmaxf(a6, a7))),
                            a8);
            float e0 = EXP2F(a0 - m), e1 = EXP2F(a1 - m), e2 = EXP2F(a2 - m);
            float e3 = EXP2F(a3 - m), e4 = EXP2F(a4 - m), e5 = EXP2F(a5 - m);
            float e6 = EXP2F(a6 - m), e7 = EXP2F(a7 - m), e8 = EXP2F(a8 - m);
            float sum = (((e0 + e1) + (e2 + e3)) + ((e4 + e5) + (e6 + e7)))
                        + e8;
            float log_norm = (m + LOG2F(sum)) * LN2;   // back to natural units
            if (lane == 0) {
                float unary  = score_parts[0] + score_parts[2];
                float binary = score_parts[1] + score_parts[3];
                ll[b] = unary + binary - log_norm;
            }
        }
    } else {
        // ---------------- Viterbi forward (bit-exact, unchanged) ----------------
        float4 c0 = *(const float4*)(rowj);
        float4 c1 = *(const float4*)(rowj + 4);
        float4 n0 = *(const float4*)(rowj + 8);
        float4 n1 = *(const float4*)(rowj + 12);

        float a0, a1, a2, a3, a4, a5, a6, a7, a8;
        a0 = rlane(c0.x, 0); a1 = rlane(c0.x, 1); a2 = rlane(c0.x, 2);
        a3 = rlane(c0.x, 3); a4 = rlane(c0.x, 4); a5 = rlane(c0.x, 5);
        a6 = rlane(c0.x, 6); a7 = rlane(c0.x, 7); a8 = rlane(c0.x, 8);

#define VSTEP(LGV, TVAL)                                                     \
        { if ((TVAL) >= len) goto vit_done;                                  \
          float s0 = a0 + trc[0], s1 = a1 + trc[1];                          \
          float s2 = a2 + trc[2], s3 = a3 + trc[3];                          \
          float s4 = a4 + trc[4], s5 = a5 + trc[5];                          \
          float s6 = a6 + trc[6], s7 = a7 + trc[7];                          \
          float s8 = a8 + trc[8];                                            \
          float c1v = (s1 > s0) ? s1 : s0;  int c1i = (s1 > s0) ? 1 : 0;    \
          float c2v = (s3 > s2) ? s3 : s2;  int c2i = (s3 > s2) ? 3 : 2;    \
          float c3v = (s5 > s4) ? s5 : s4;  int c3i = (s5 > s4) ? 5 : 4;    \
          float c4v = (s7 > s6) ? s7 : s6;  int c4i = (s7 > s6) ? 7 : 6;    \
          float d1v = (c2v > c1v) ? c2v : c1v;  int d1i = (c2v > c1v) ? c2i : c1i; \
          float d2v = (c4v > c3v) ? c4v : c3v;  int d2i = (c4v > c3v) ? c4i : c3i; \
          float e1v = (d2v > d1v) ? d2v : d1v;  int e1i = (d2v > d1v) ? d2i : d1i; \
          float bv  = (s8 > e1v) ? s8 : e1v;    int bi  = (s8 > e1v) ? 8 : e1i;    \
          if (lane < LL) bpB[TVAL][lane] = (unsigned char)bi;                \
          float ns = bv + (LGV);                                             \
          a0 = rlane(ns, 0); a1 = rlane(ns, 1); a2 = rlane(ns, 2);           \
          a3 = rlane(ns, 3); a4 = rlane(ns, 4); a5 = rlane(ns, 5);           \
          a6 = rlane(ns, 6); a7 = rlane(ns, 7); a8 = rlane(ns, 8); }

        VSTEP(c0.y, 1) VSTEP(c0.z, 2) VSTEP(c0.w, 3)
        VSTEP(c1.x, 4) VSTEP(c1.y, 5) VSTEP(c1.z, 6) VSTEP(c1.w, 7)

        for (int cb = 8; cb < TT; cb += 8) {
            c0 = n0; c1 = n1;
            if (cb + 8 < TT) {
                n0 = *(const float4*)(rowj + cb + 8);
                n1 = *(const float4*)(rowj + cb + 12);
            }
            VSTEP(c0.x, cb + 0) VSTEP(c0.y, cb + 1)
            VSTEP(c0.z, cb + 2) VSTEP(c0.w, cb + 3)
            VSTEP(c1.x, cb + 4) VSTEP(c1.y, cb + 5)
            VSTEP(c1.z, cb + 6) VSTEP(c1.w, cb + 7)
        }
vit_done: ;
        // last_tag = first-max argmax of final state
        int last_tag;
        {
            float s0 = a0, s1 = a1, s2 = a2, s3 = a3;
            float s4 = a4, s5 = a5, s6 = a6, s7 = a7, s8 = a8;
            float c1v = (s1 > s0) ? s1 : s0;  int c1i = (s1 > s0) ? 1 : 0;
            float c2v = (s3 > s2) ? s3 : s2;  int c2i = (s3 > s2) ? 3 : 2;
            float c3v = (s5 > s4) ? s5 : s4;  int c3i = (s5 > s4) ? 5 : 4;
            float c4v = (s7 > s6) ? s7 : s6;  int c4i = (s7 > s6) ? 7 : 6;
            float d1v = (c2v > c1v) ? c2v : c1v;  int d1i = (c2v > c1v) ? c2i : c1i;
            float d2v = (c4v > c3v) ? c4v : c3v;  int d2i = (c4v > c3v) ? c4i : c3i;
            float e1v = (d2v > d1v) ? d2v : d1v;  int e1i = (d2v > d1v) ? d2i : d1i;
            last_tag = (s8 > e1v) ? 8 : e1i;
        }

        // ---------------- compose-based parallel backtrace ----------------
        const unsigned long long IDENT = 0x876543210ULL;
        unsigned long long f[8];
        const int t0 = lane * 8;
#pragma unroll
        for (int m2 = 0; m2 < 8; ++m2) {
            int t = t0 + m2;
            unsigned long long F = IDENT;
            if (t >= 1 && t < len) {
                F = 0ULL;
#pragma unroll
                for (int jj = 0; jj < LL; ++jj)
                    F |= ((unsigned long long)bpB[t][jj]) << (4 * jj);
            }
            f[m2] = F;
        }
        unsigned long long h = f[7];
#pragma unroll
        for (int m2 = 6; m2 >= 0; --m2) {
            unsigned long long hn = 0ULL;
#pragma unroll
            for (int jj = 0; jj < LL; ++jj) {
                int v = (int)((h >> (4 * jj)) & 15ULL);
                int w = (int)((f[m2] >> (4 * v)) & 15ULL);
                hn |= ((unsigned long long)w) << (4 * jj);
            }
            h = hn;
        }
        const unsigned hlo = (unsigned)h, hhi = (unsigned)(h >> 32);
        int tag = last_tag;
        int entry = last_tag;
        for (int l2 = 63; l2 >= 0; --l2) {
            unsigned glo = (unsigned)__builtin_amdgcn_readlane((int)hlo, l2);
            unsigned ghi = (unsigned)__builtin_amdgcn_readlane((int)hhi, l2);
            unsigned long long g = ((unsigned long long)ghi << 32) | glo;
            if (l2 == lane) entry = tag;
            tag = (int)((g >> (4 * tag)) & 15ULL);
        }
        float* dec = out_decode + (size_t)b * TT;
        int e = entry;
        {
            int t = t0 + 7;
            dec[t] = (t < len) ? (float)e : 0.f;
        }
#pragma unroll
        for (int m2 = 7; m2 >= 1; --m2) {
            e = (int)((f[m2] >> (4 * e)) & 15ULL);
            int t = t0 + m2 - 1;
            dec[t] = (t < len) ? (float)e : 0.f;
        }
    }
}

// ---------------------------------------------------------------------------
// Kernel C: loss = -mean(ll)
// ---------------------------------------------------------------------------
__global__ __launch_bounds__(64) void loss_kernel(const float* __restrict__ ll,
                                                  float* __restrict__ out)
{
    const int lane = threadIdx.x;
    float v = ll[lane];
#pragma unroll
    for (int off = 32; off; off >>= 1) v += __shfl_xor(v, off, 64);
    if (lane == 0) out[0] = -v * (1.0f / 64.0f);
}

extern "C" void kernel_launch(void* const* d_in, const int* in_sizes, int n_in,
                              void* d_out, int out_size, void* d_ws, size_t ws_size,
                              hipStream_t stream)
{
    const float* hidden  = (const float*)d_in[0];
    const float* W       = (const float*)d_in[1];
    const float* bias    = (const float*)d_in[2];
    const float* trans   = (const float*)d_in[3];
    const int*   tags    = (const int*)d_in[4];
    const int*   lengths = (const int*)d_in[5];

    float* out = (float*)d_out;
    float* logits = (float*)d_ws;                       // 32768*9 floats
    float* ll     = logits + (size_t)BB * TT * LL;      // 64 floats

    logits_kernel<<<2048, 256, 0, stream>>>(hidden, W, bias, logits);
    crf_kernel<<<BB, 128, 0, stream>>>(logits, trans, tags, lengths, ll, out + 1);
    loss_kernel<<<1, 64, 0, stream>>>(ll, out);
}